// Round 5
// baseline (166.771 us; speedup 1.0000x reference)
//
#include <hip/hip_runtime.h>
#include <stdint.h>

static constexpr int Kdim  = 1024;    // L
static constexpr int Ncols = 512;     // OUT

typedef __attribute__((ext_vector_type(8))) short bf16x8;
typedef __attribute__((ext_vector_type(4))) float f32x4;
typedef __attribute__((ext_vector_type(4))) unsigned int u32x4;

__device__ __forceinline__ unsigned short f2bf(float f) {
  unsigned u = __builtin_bit_cast(unsigned, f);
  u += 0x7FFFu + ((u >> 16) & 1u);          // RNE
  return (unsigned short)(u >> 16);
}
__device__ __forceinline__ unsigned f2bf2(float lo, float hi) {
  unsigned ul = __builtin_bit_cast(unsigned, lo);
  unsigned uh = __builtin_bit_cast(unsigned, hi);
  ul += 0x7FFFu + ((ul >> 16) & 1u);
  uh += 0x7FFFu + ((uh >> 16) & 1u);
  return (ul >> 16) | (uh & 0xFFFF0000u);
}

// async global->LDS, 16B per lane; LDS dest = uniform base + lane*16,
// global source is PER-LANE (swizzle goes on the source address)
__device__ __forceinline__ void gl2lds16(const void* g, void* l) {
  __builtin_amdgcn_global_load_lds(
      (const __attribute__((address_space(1))) void*)g,
      (__attribute__((address_space(3))) void*)l, 16, 0, 0);
}

// ---------------------------------------------------------------------------
// prep_w: 512 blocks: Wt[n][k] = bf16(0.5*(W_in+W_out)+W_root)^T.  ~7 MiB.
// ---------------------------------------------------------------------------
__global__ __launch_bounds__(256) void prep_w(
    const float* __restrict__ Win, const float* __restrict__ Wout,
    const float* __restrict__ Wroot, unsigned short* __restrict__ Wt)
{
  __shared__ unsigned short lds[32 * 36];
  const int t  = threadIdx.x;
  const int b2 = blockIdx.x;
  const int tk0 = (b2 & 31) * 32;
  const int tn0 = (b2 >> 5) * 32;
  {
    const int k  = t >> 3;
    const int nq = (t & 7) * 4;
    const int gi = (tk0 + k) * Ncols + tn0 + nq;
    const float4 wi = *(const float4*)(Win + gi);
    const float4 wo = *(const float4*)(Wout + gi);
    const float4 wr = *(const float4*)(Wroot + gi);
    lds[(nq + 0) * 36 + k] = f2bf(0.5f * (wi.x + wo.x) + wr.x);
    lds[(nq + 1) * 36 + k] = f2bf(0.5f * (wi.y + wo.y) + wr.y);
    lds[(nq + 2) * 36 + k] = f2bf(0.5f * (wi.z + wo.z) + wr.z);
    lds[(nq + 3) * 36 + k] = f2bf(0.5f * (wi.w + wo.w) + wr.w);
  }
  __syncthreads();
  {
    const int n  = t >> 3;
    const int k8 = (t & 7) * 4;
    const ushort4 v = *(const ushort4*)&lds[n * 36 + k8];
    *(ushort4*)(Wt + (size_t)(tn0 + n) * Kdim + tk0 + k8) = v;
  }
}

// ---------------------------------------------------------------------------
// gemm_direct: Y = bf16(x) @ Wt^T + bias.  64m x 128n tiles, BK=32,
// 1024 blocks (4/CU, 16 waves/CU), 4 waves, wave = 16m x 128n
// (1 A-frag x 8 B-frags, 8 mfma_f32_16x16x32_bf16 per k-step).
//
// KEY: A is staged as RAW F32 via global_load_lds (no prep pass, no reg-pack
// path).  f32->bf16 conversion happens at FRAGMENT READ time (2x ds_read_b128
// + 4 f2bf2 per wave per k-step).  Loop stays pure-gl2lds: exactly 4
// wave-level vm ops/iter -> exact counted vmcnt.
//   A LDS layout: rows of 128 B (32 f32); 16B slot s of row r holds global
//   chunk s^(r&7) (swizzle on the per-lane GLOBAL source; LDS dest linear).
//   Frag read: lane(q=lane>>4, lm=lane&15) reads slots (2q)^(lm&7) and
//   (2q+1)^(lm&7) of row lm -> 8 lanes/slot = 2 lanes/bank = conflict-free.
// Buffers: A triple (2-ahead covers HBM/L3 latency), B double (1-ahead, Wt
// is L2-hot).  LDS = 3*8K + 2*8K = 40960 B -> exactly 4 blocks/CU.
// Per iter: STAGE_B(t+1); STAGE_A(t+2); frags+convert+8 MFMA;
//   s_waitcnt vmcnt(2) (B(t+1)+A(t+1) landed, A(t+2) in flight); s_barrier.
// Block map keeps the 4 n-sharers of an m-panel on ONE XCD (x L2 reuse):
//   xcd=bid&7, s=bid>>3, mt=xcd*32+(s>>2), nt=s&3.
// ---------------------------------------------------------------------------
__global__ __launch_bounds__(256, 4) void gemm_direct(
    const float* __restrict__ x, const unsigned short* __restrict__ Wt,
    const float* __restrict__ b_in, const float* __restrict__ b_out,
    const float* __restrict__ b_root, float* __restrict__ Y)
{
  __shared__ __attribute__((aligned(16))) float Asf[3][64][32];   // 24 KB
  __shared__ __attribute__((aligned(16))) short Bs[2][128][32];   // 16 KB

  const int bid = blockIdx.x;
  const int xcd = bid & 7;
  const int s   = bid >> 3;                  // 0..127
  const int mt  = xcd * 32 + (s >> 2);       // 0..255
  const int nt  = s & 3;
  const int m0  = mt * 64;
  const int n0  = nt * 128;

  const int t    = threadIdx.x;
  const int lane = t & 63;
  const int w    = t >> 6;
  const int quad = lane >> 4;
  const int lm   = lane & 15;

  // --- A staging: wave w covers rows w*16..w*16+15 (2 gl2lds x 8 rows).
  //     lane: row-in-8 = lane>>3, slot = lane&7, source chunk = slot^(row&7)
  //     ((row&7) == (lane>>3)&7 for both 8-row halves).
  const int al  = lane >> 3;
  const int asl = lane & 7;
  const int asc = asl ^ al;
  const float* gA0 = x + (size_t)(m0 + w * 16 + al) * Kdim + asc * 4;
  const float* gA1 = gA0 + (size_t)8 * Kdim;

  // --- B staging (verified layout): wave w covers rows w*32..w*32+31,
  //     slot s of row r holds chunk s^((r>>1)&3) via swizzled source.
  const int sr = lane >> 2;
  const int ss = lane & 3;
  const int sc = ss ^ ((sr >> 1) & 3);
  const unsigned short* gB = Wt + (size_t)(n0 + w * 32 + sr) * Kdim + sc * 8;
  const int rowK = 16 * Kdim;

  // --- fragment offsets
  const int a0off = (w * 16 + lm) * 32 + ((2 * quad)     ^ (lm & 7)) * 4;  // floats
  const int a1off = (w * 16 + lm) * 32 + ((2 * quad + 1) ^ (lm & 7)) * 4;
  const int boff  = lm * 32 + (quad ^ ((lm >> 1) & 3)) * 8;                // + j*512 shorts

  f32x4 acc[8] = {};

#define STAGE_B(TT, BB) do {                                              \
    gl2lds16(gB + (TT) * 32,        &Bs[BB][w * 32][0]);                  \
    gl2lds16(gB + (TT) * 32 + rowK, &Bs[BB][w * 32 + 16][0]);             \
  } while (0)

#define STAGE_A(TT, AB) do {                                              \
    gl2lds16(gA0 + (TT) * 32, &Asf[AB][w * 16][0]);                       \
    gl2lds16(gA1 + (TT) * 32, &Asf[AB][w * 16 + 8][0]);                   \
  } while (0)

  // prologue: queue = [B0,B0,A0,A0,A1,A1]; vmcnt(2) -> B0,A0 landed, A1 flies
  STAGE_B(0, 0);
  __builtin_amdgcn_sched_barrier(0);
  STAGE_A(0, 0);
  STAGE_A(1, 1);
  asm volatile("s_waitcnt vmcnt(2)" ::: "memory");
  __builtin_amdgcn_s_barrier();
  __builtin_amdgcn_sched_barrier(0);

  #pragma unroll 1
  for (int it = 0; it < 32; ++it) {
    // stage next B (older in vm queue) then next-next A; clamp at the tail
    const int tb = (it + 1 < 32) ? it + 1 : 31;
    const int ta = (it + 2 < 32) ? it + 2 : 31;
    STAGE_B(tb, (it + 1) & 1);
    __builtin_amdgcn_sched_barrier(0);       // B stays older than A in queue
    STAGE_A(ta, (it + 2) % 3);
    __builtin_amdgcn_sched_barrier(0);

    // A frag: 2x ds_read_b128 f32 + convert to bf16x8
    const float* ab = &Asf[it % 3][0][0];
    const f32x4 c0 = *(const f32x4*)(ab + a0off);
    const f32x4 c1 = *(const f32x4*)(ab + a1off);
    u32x4 ua;
    ua.x = f2bf2(c0.x, c0.y); ua.y = f2bf2(c0.z, c0.w);
    ua.z = f2bf2(c1.x, c1.y); ua.w = f2bf2(c1.z, c1.w);
    const bf16x8 af = __builtin_bit_cast(bf16x8, ua);

    const short* bb = &Bs[it & 1][0][0];
    bf16x8 bfr[8];
    #pragma unroll
    for (int j = 0; j < 8; ++j)
      bfr[j] = *(const bf16x8*)(bb + boff + j * 512);

    #pragma unroll
    for (int j = 0; j < 8; ++j)
      acc[j] = __builtin_amdgcn_mfma_f32_16x16x32_bf16(af, bfr[j], acc[j], 0, 0, 0);

    // drain B(it+1) + A(it+1); keep A(it+2) in flight
    asm volatile("s_waitcnt vmcnt(2)" ::: "memory");
    __builtin_amdgcn_s_barrier();
    __builtin_amdgcn_sched_barrier(0);
  }

  // drain the clamped duplicate staging ops before we exit
  asm volatile("s_waitcnt vmcnt(0)" ::: "memory");

#undef STAGE_A
#undef STAGE_B

  // epilogue: D[row=quad*4+reg][col=lm] per 16x16 frag; bias fused
  #pragma unroll
  for (int j = 0; j < 8; ++j) {
    const int gc = n0 + j * 16 + lm;
    const float bias = 0.5f * (b_in[gc] + b_out[gc]) + b_root[gc];
    const int gr = m0 + w * 16 + quad * 4;
    float* yp = Y + (size_t)gr * Ncols + gc;
    #pragma unroll
    for (int r = 0; r < 4; ++r)
      yp[(size_t)r * Ncols] = acc[j][r] + bias;
  }
}

// ---------------------------------------------------------------------------
extern "C" void kernel_launch(void* const* d_in, const int* in_sizes, int n_in,
                              void* d_out, int out_size, void* d_ws, size_t ws_size,
                              hipStream_t stream)
{
  const float* x      = (const float*)d_in[0];
  // d_in[1] = At : dead input (ChebConv K=1 -> no neighbor aggregation)
  const float* W_in   = (const float*)d_in[2];
  const float* b_in   = (const float*)d_in[3];
  const float* W_out  = (const float*)d_in[4];
  const float* b_out  = (const float*)d_in[5];
  const float* W_root = (const float*)d_in[6];
  const float* b_root = (const float*)d_in[7];
  float* y = (float*)d_out;

  unsigned short* Wt = (unsigned short*)d_ws;   // 1 MiB only

  prep_w<<<dim3(512), dim3(256), 0, stream>>>(W_in, W_out, W_root, Wt);
  gemm_direct<<<dim3(1024), dim3(256), 0, stream>>>(x, Wt, b_in, b_out, b_root, y);
}